// Round 1
// baseline (74654.559 us; speedup 1.0000x reference)
//
#include <hip/hip_runtime.h>
#include <hip/hip_cooperative_groups.h>
#include <math.h>

namespace cg = cooperative_groups;

#define LSEQ 128
#define BATCH 64
#define EDIM 512
#define HDIM 1024
#define N3 3072   // 3*H
#define NWG 256
#define NTH 512

// ---------------------------------------------------------------------------
// f32 tiled GEMM with optional row-gather on A:  C[M,N] = A[idx][K] @ Bm[K,N] + bias
// Tile 64x64, BK=32, 256 threads, 4x4 micro-tile per thread.
// M, N multiples of 64; K multiple of 32 (512 or 1024 here).
// ---------------------------------------------------------------------------
__global__ __launch_bounds__(256) void gemm_bias(
    const float* __restrict__ A, const int* __restrict__ idx, int K,
    const float* __restrict__ Bm, const float* __restrict__ bias,
    float* __restrict__ C, int N)
{
    __shared__ float As[32][68];
    __shared__ float Bs[32][68];
    const int tid = threadIdx.x;
    const int m0 = blockIdx.y * 64, n0 = blockIdx.x * 64;
    const int ty = tid >> 4, tx = tid & 15;

    float acc[4][4] = {};

    const int ra = tid >> 3;            // 0..31  (A rows per half)
    const int kq = (tid & 7) << 2;      // 0,4,...,28
    const int kb = tid >> 4;            // 0..15  (B k rows per half)
    const int nq = (tid & 15) << 2;     // 0..60

    for (int k0 = 0; k0 < K; k0 += 32) {
        #pragma unroll
        for (int h2 = 0; h2 < 2; ++h2) {
            const int row = ra + h2 * 32;
            const int grow = idx ? idx[m0 + row] : (m0 + row);
            const float4 v = *reinterpret_cast<const float4*>(&A[(size_t)grow * K + k0 + kq]);
            As[kq + 0][row] = v.x; As[kq + 1][row] = v.y;
            As[kq + 2][row] = v.z; As[kq + 3][row] = v.w;
        }
        #pragma unroll
        for (int h2 = 0; h2 < 2; ++h2) {
            const int kk = kb + h2 * 16;
            *reinterpret_cast<float4*>(&Bs[kk][nq]) =
                *reinterpret_cast<const float4*>(&Bm[(size_t)(k0 + kk) * N + n0 + nq]);
        }
        __syncthreads();
        #pragma unroll
        for (int k = 0; k < 32; ++k) {
            const float4 a4 = *reinterpret_cast<const float4*>(&As[k][ty * 4]);
            const float4 b4 = *reinterpret_cast<const float4*>(&Bs[k][tx * 4]);
            const float av[4] = {a4.x, a4.y, a4.z, a4.w};
            const float bv[4] = {b4.x, b4.y, b4.z, b4.w};
            #pragma unroll
            for (int i = 0; i < 4; ++i)
                #pragma unroll
                for (int j = 0; j < 4; ++j)
                    acc[i][j] += av[i] * bv[j];
        }
        __syncthreads();
    }
    #pragma unroll
    for (int i = 0; i < 4; ++i) {
        const int m = m0 + ty * 4 + i;
        #pragma unroll
        for (int j = 0; j < 4; ++j) {
            const int n = n0 + tx * 4 + j;
            C[(size_t)m * N + n] = acc[i][j] + bias[n];
        }
    }
}

// ---------------------------------------------------------------------------
// Cooperative persistent GRU scan.
// 256 WGs x 512 threads. WG g owns gate columns j = 4g..4g+3:
//   LDS-resident Whzr columns {j, 1024+j} (8 cols, 32KB) and Whh columns {j} (16KB).
// Per step: phase A computes z_j, r_j*h_j for all 64 batch rows (K=1024 dots
// against LDS weights), grid sync, phase B computes the candidate GEMM column,
// tanh, and the gated h update. 2 grid syncs per step.
// ---------------------------------------------------------------------------
__global__ __launch_bounds__(NTH) void gru_scan(
    const float* __restrict__ gx,     // [L*B*3072] precomputed x@Wx + bx
    const float* __restrict__ Whzr,   // [1024,2048]
    const float* __restrict__ bhzr,   // [2048]
    const float* __restrict__ Whh,    // [1024,1024]
    const float* __restrict__ bhh,    // [1024]
    const float* __restrict__ mask,   // [L*B]
    float* __restrict__ h,            // [B*H]  (zeroed before launch)
    float* __restrict__ zbuf,         // [B*H]
    float* __restrict__ rhbuf,        // [B*H]
    float* __restrict__ out,          // [L*B*H]
    int reverse)
{
    __shared__ float Wzr_l[8][1028];
    __shared__ float Whh_l[4][1028];
    cg::grid_group grid = cg::this_grid();
    const int wg = blockIdx.x, tid = threadIdx.x;

    // Stage owned weight columns into LDS (one-time, strided global reads).
    #pragma unroll
    for (int c = 0; c < 8; ++c) {
        const int col = wg * 4 + (c & 3) + ((c >> 2) << 10);
        for (int k = tid; k < HDIM; k += NTH)
            Wzr_l[c][k] = Whzr[(size_t)k * 2048 + col];
    }
    #pragma unroll
    for (int c = 0; c < 4; ++c) {
        const int col = wg * 4 + c;
        for (int k = tid; k < HDIM; k += NTH)
            Whh_l[c][k] = Whh[(size_t)k * HDIM + col];
    }
    __threadfence();
    grid.sync();

    // Phase A mapping: tid = c8*64 + b  (c8: 0..3 -> z cols, 4..7 -> r cols)
    const int c8 = tid >> 6;
    const int bA = tid & 63;
    const int jA = wg * 4 + (c8 & 3);
    const int gcolA = jA + ((c8 >> 2) << 10);
    // Phase B mapping: tid = c4*128 + b*2 + kh  (split-K over 2 halves)
    const int c4 = tid >> 7;
    const int bB = (tid >> 1) & 63;
    const int kh = tid & 1;
    const int mB = wg * 4 + c4;

    for (int s = 0; s < LSEQ; ++s) {
        const int t = reverse ? (LSEQ - 1 - s) : s;

        // ---------- phase A: gh_zr columns, gates, r*h ----------
        {
            const float* hrow = h + bA * HDIM;
            const float* wcol = Wzr_l[c8];
            float acc = 0.f;
            #pragma unroll 8
            for (int k = 0; k < HDIM; k += 4) {
                const float4 hv = *reinterpret_cast<const float4*>(hrow + k);
                const float4 wv = *reinterpret_cast<const float4*>(wcol + k);
                acc += hv.x * wv.x + hv.y * wv.y + hv.z * wv.z + hv.w * wv.w;
            }
            const float pre = acc + bhzr[gcolA]
                            + gx[((size_t)t * BATCH + bA) * N3 + gcolA];
            const float sig = 1.f / (1.f + expf(-pre));
            if (c8 < 4) zbuf[bA * HDIM + jA] = sig;
            else        rhbuf[bA * HDIM + jA] = sig * h[bA * HDIM + jA];
        }
        __threadfence();
        grid.sync();

        // ---------- phase B: candidate column, h update ----------
        {
            const float* rrow = rhbuf + bB * HDIM + kh * 512;
            const float* wcol = Whh_l[c4] + kh * 512;
            float acc = 0.f;
            #pragma unroll 8
            for (int k = 0; k < 512; k += 4) {
                const float4 rv = *reinterpret_cast<const float4*>(rrow + k);
                const float4 wv = *reinterpret_cast<const float4*>(wcol + k);
                acc += rv.x * wv.x + rv.y * wv.y + rv.z * wv.z + rv.w * wv.w;
            }
            acc += __shfl_xor(acc, 1, 64);
            const float pre = acc + bhh[mB]
                            + gx[((size_t)t * BATCH + bB) * N3 + 2048 + mB];
            const float hc = tanhf(pre);
            const float zv = zbuf[bB * HDIM + mB];
            const float ho = h[bB * HDIM + mB];
            float hn = ho + zv * (hc - ho);           // (1-z)h + z*hc
            const float mk = mask[t * BATCH + bB];
            hn = ho + mk * (hn - ho);                  // mask blend
            if (kh == 0) {
                h[bB * HDIM + mB] = hn;
                out[((size_t)t * BATCH + bB) * HDIM + mB] = hn;
            }
        }
        __threadfence();
        grid.sync();
    }
}

// ---------------------------------------------------------------------------
extern "C" void kernel_launch(void* const* d_in, const int* in_sizes, int n_in,
                              void* d_out, int out_size, void* d_ws, size_t ws_size,
                              hipStream_t stream) {
    const int*   xs      = (const int*)  d_in[0];
    const float* xs_mask = (const float*)d_in[1];
    const float* emb     = (const float*)d_in[2];
    const float* fw_Wx   = (const float*)d_in[3];
    const float* fw_bx   = (const float*)d_in[4];
    const float* fw_Whzr = (const float*)d_in[5];
    const float* fw_bhzr = (const float*)d_in[6];
    const float* fw_Whh  = (const float*)d_in[7];
    const float* fw_bhh  = (const float*)d_in[8];
    const float* bw_Wx   = (const float*)d_in[9];
    const float* bw_bx   = (const float*)d_in[10];
    const float* bw_Whzr = (const float*)d_in[11];
    const float* bw_bhzr = (const float*)d_in[12];
    const float* bw_Whh  = (const float*)d_in[13];
    const float* bw_bhh  = (const float*)d_in[14];
    float* outp = (float*)d_out;

    // workspace carve
    char* w = (char*)d_ws;
    float* gxbuf = (float*)w; w += (size_t)LSEQ * BATCH * N3 * sizeof(float); // 100.7MB
    float* hbuf  = (float*)w; w += (size_t)BATCH * HDIM * sizeof(float);
    float* zb    = (float*)w; w += (size_t)BATCH * HDIM * sizeof(float);
    float* rb    = (float*)w; w += (size_t)BATCH * HDIM * sizeof(float);

    const dim3 gemm_grid(N3 / 64, (LSEQ * BATCH) / 64);  // (48, 128)
    const dim3 gemm_blk(256);

    // ---- forward direction ----
    hipMemsetAsync(hbuf, 0, (size_t)BATCH * HDIM * sizeof(float), stream);
    {
        // gx = emb[xs] @ fw_Wx + fw_bx
        hipLaunchKernelGGL(gemm_bias, gemm_grid, gemm_blk, 0, stream,
                           emb, xs, EDIM, fw_Wx, fw_bx, gxbuf, N3);
    }
    {
        int rev = 0;
        void* args[] = {(void*)&gxbuf, (void*)&fw_Whzr, (void*)&fw_bhzr,
                        (void*)&fw_Whh, (void*)&fw_bhh, (void*)&xs_mask,
                        (void*)&hbuf, (void*)&zb, (void*)&rb,
                        (void*)&outp, (void*)&rev};
        hipLaunchCooperativeKernel((const void*)gru_scan, dim3(NWG), dim3(NTH),
                                   args, 0, stream);
    }

    // ---- backward direction ----
    hipMemsetAsync(hbuf, 0, (size_t)BATCH * HDIM * sizeof(float), stream);
    {
        // gx = right(@d_out) @ bw_Wx + bw_bx
        const float* rightp = (const float*)d_out;
        const int* noidx = nullptr;
        hipLaunchKernelGGL(gemm_bias, gemm_grid, gemm_blk, 0, stream,
                           rightp, noidx, HDIM, bw_Wx, bw_bx, gxbuf, N3);
    }
    {
        int rev = 1;
        void* args[] = {(void*)&gxbuf, (void*)&bw_Whzr, (void*)&bw_bhzr,
                        (void*)&bw_Whh, (void*)&bw_bhh, (void*)&xs_mask,
                        (void*)&hbuf, (void*)&zb, (void*)&rb,
                        (void*)&outp, (void*)&rev};
        hipLaunchCooperativeKernel((const void*)gru_scan, dim3(NWG), dim3(NTH),
                                   args, 0, stream);
    }
}

// Round 2
// 8108.559 us; speedup vs baseline: 9.2069x; 9.2069x over previous
//
#include <hip/hip_runtime.h>
#include <math.h>

#define LSEQ 128
#define BATCH 64
#define EDIM 512
#define HDIM 1024
#define N3 3072
#define NWG 256
#define NTH 512
#define GXT ((size_t)(BATCH * N3))   // floats per time step in gx

// ---------------------------------------------------------------------------
// agent-scope (cross-XCD coherent) scalar load/store: bypass non-coherent L2
// ---------------------------------------------------------------------------
__device__ __forceinline__ float sc1Ld(const float* p) {
    return __hip_atomic_load(p, __ATOMIC_RELAXED, __HIP_MEMORY_SCOPE_AGENT);
}
__device__ __forceinline__ void sc1St(float* p, float v) {
    __hip_atomic_store(p, v, __ATOMIC_RELAXED, __HIP_MEMORY_SCOPE_AGENT);
}

// Lightweight grid barrier: per-barrier-instance counter (pre-zeroed).
// All communicated data is written with sc1 stores; __syncthreads drains each
// wave's vmcnt, so by the time thread 0 increments the counter all of this
// WG's data is visible at the coherent point. No L2 writeback/inv needed.
__device__ __forceinline__ void grid_bar(int* cnt) {
    __syncthreads();
    if (threadIdx.x == 0) {
        asm volatile("s_waitcnt vmcnt(0)" ::: "memory");
        __hip_atomic_fetch_add(cnt, 1, __ATOMIC_RELAXED, __HIP_MEMORY_SCOPE_AGENT);
        while (__hip_atomic_load(cnt, __ATOMIC_RELAXED, __HIP_MEMORY_SCOPE_AGENT) != NWG) {}
        asm volatile("" ::: "memory");
    }
    __syncthreads();
}

// ---------------------------------------------------------------------------
// f32 tiled GEMM with optional row-gather on A (unchanged from round 1).
// ---------------------------------------------------------------------------
__global__ __launch_bounds__(256) void gemm_bias(
    const float* __restrict__ A, const int* __restrict__ idx, int K,
    const float* __restrict__ Bm, const float* __restrict__ bias,
    float* __restrict__ C, int N)
{
    __shared__ float As[32][68];
    __shared__ float Bs[32][68];
    const int tid = threadIdx.x;
    const int m0 = blockIdx.y * 64, n0 = blockIdx.x * 64;
    const int ty = tid >> 4, tx = tid & 15;

    float acc[4][4] = {};

    const int ra = tid >> 3;
    const int kq = (tid & 7) << 2;
    const int kb = tid >> 4;
    const int nq = (tid & 15) << 2;

    for (int k0 = 0; k0 < K; k0 += 32) {
        #pragma unroll
        for (int h2 = 0; h2 < 2; ++h2) {
            const int row = ra + h2 * 32;
            const int grow = idx ? idx[m0 + row] : (m0 + row);
            const float4 v = *reinterpret_cast<const float4*>(&A[(size_t)grow * K + k0 + kq]);
            As[kq + 0][row] = v.x; As[kq + 1][row] = v.y;
            As[kq + 2][row] = v.z; As[kq + 3][row] = v.w;
        }
        #pragma unroll
        for (int h2 = 0; h2 < 2; ++h2) {
            const int kk = kb + h2 * 16;
            *reinterpret_cast<float4*>(&Bs[kk][nq]) =
                *reinterpret_cast<const float4*>(&Bm[(size_t)(k0 + kk) * N + n0 + nq]);
        }
        __syncthreads();
        #pragma unroll
        for (int k = 0; k < 32; ++k) {
            const float4 a4 = *reinterpret_cast<const float4*>(&As[k][ty * 4]);
            const float4 b4 = *reinterpret_cast<const float4*>(&Bs[k][tx * 4]);
            const float av[4] = {a4.x, a4.y, a4.z, a4.w};
            const float bv[4] = {b4.x, b4.y, b4.z, b4.w};
            #pragma unroll
            for (int i = 0; i < 4; ++i)
                #pragma unroll
                for (int j = 0; j < 4; ++j)
                    acc[i][j] += av[i] * bv[j];
        }
        __syncthreads();
    }
    #pragma unroll
    for (int i = 0; i < 4; ++i) {
        const int m = m0 + ty * 4 + i;
        #pragma unroll
        for (int j = 0; j < 4; ++j) {
            const int n = n0 + tx * 4 + j;
            C[(size_t)m * N + n] = acc[i][j] + bias[n];
        }
    }
}

// ---------------------------------------------------------------------------
// GRU scan v2. 256 WGs x 512 threads, WG g owns gate columns 4g..4g+3.
// Weights LDS-resident in [k][col] layout (row broadcast -> conflict-free).
// Cross-WG per-step data overlaid TRANSPOSED into gx's dead z/r regions:
//   hT(t,j,b)  = gx[t][j>>4][       (j&15)*64 + b]   (z region, dead after A)
//   rhT(t,j,b) = gx[t][j>>4][1024 + (j&15)*64 + b]   (r region, dead after A)
// Writers use sc1 stores; phase-A consumption of gx z/r uses sc1 loads (so no
// cache lines are ever allocated before the overlay writes); post-barrier
// readers use plain cached b128 loads at these fresh addresses.
// ---------------------------------------------------------------------------
__global__ __launch_bounds__(NTH) void gru_scan2(
    float* __restrict__ gx,           // [L][B][3072]
    const float* __restrict__ Whzr,   // [1024][2048]
    const float* __restrict__ bhzr,   // [2048]
    const float* __restrict__ Whh,    // [1024][1024]
    const float* __restrict__ bhh,    // [1024]
    const float* __restrict__ mask,   // [L][B]
    float* __restrict__ out,          // [L][B][1024]
    int* __restrict__ bar,            // [2*LSEQ] pre-zeroed counters
    int reverse)
{
    __shared__ float Wzr_l[HDIM * 8];   // [k][8]: cols {4g..4g+3, 1024+4g..}
    __shared__ float Whh_l[HDIM * 4];   // [k][4]
    __shared__ float part[8704];        // reduce scratch (A: 8x512, B: 32x260)
    __shared__ float zl[BATCH * 4];     // z gate, this WG's 4 cols
    __shared__ float hold[BATCH * 4];   // h_old at this WG's 4 cols

    const int wg = blockIdx.x, tid = threadIdx.x;
    const int w = tid >> 6, lane = tid & 63;
    const int b4 = lane >> 2, c2 = lane & 3;

    // ---- one-time: stage owned weight columns into LDS (coalesced float4) ----
    for (int k = tid; k < HDIM; k += NTH) {
        float4 a = *(const float4*)&Whzr[(size_t)k * 2048 + wg * 4];
        float4 b = *(const float4*)&Whzr[(size_t)k * 2048 + 1024 + wg * 4];
        *(float4*)&Wzr_l[k * 8]     = a;
        *(float4*)&Wzr_l[k * 8 + 4] = b;
        *(float4*)&Whh_l[k * 4] = *(const float4*)&Whh[(size_t)k * HDIM + wg * 4];
    }
    __syncthreads();

    for (int s = 0; s < LSEQ; ++s) {
        const int t  = reverse ? (LSEQ - 1 - s) : s;
        const int tp = reverse ? (t + 1) : (t - 1);

        // ================= phase A: z, r, r*h =================
        // stage h_old at this WG's 4 candidate columns into LDS
        if (tid < 64) {
            const int jj = tid >> 4, bq = tid & 15;
            float4 h4 = make_float4(0.f, 0.f, 0.f, 0.f);
            if (s > 0) {
                const int j = wg * 4 + jj;
                h4 = *(const float4*)&gx[(size_t)tp * GXT + (size_t)(j >> 4) * 3072
                                         + (j & 15) * 64 + 4 * bq];
            }
            hold[(4 * bq + 0) * 4 + jj] = h4.x;
            hold[(4 * bq + 1) * 4 + jj] = h4.y;
            hold[(4 * bq + 2) * 4 + jj] = h4.z;
            hold[(4 * bq + 3) * 4 + jj] = h4.w;
        }

        // register-tiled partial GEMM: wave w covers K-slice [128w,128w+128)
        float acc[4][2] = {{0.f,0.f},{0.f,0.f},{0.f,0.f},{0.f,0.f}};
        if (s > 0) {
            const float* hb = gx + (size_t)tp * GXT;
            for (int kb = 0; kb < 8; ++kb) {
                const float* rowb = hb + (size_t)(w * 8 + kb) * 3072;
                const float* wrow = &Wzr_l[(w * 128 + kb * 16) * 8 + 2 * c2];
                #pragma unroll
                for (int kk = 0; kk < 16; ++kk) {
                    const float4 h4 = *(const float4*)(rowb + kk * 64 + 4 * b4);
                    const float2 w2 = *(const float2*)(wrow + kk * 8);
                    acc[0][0] += h4.x * w2.x; acc[0][1] += h4.x * w2.y;
                    acc[1][0] += h4.y * w2.x; acc[1][1] += h4.y * w2.y;
                    acc[2][0] += h4.z * w2.x; acc[2][1] += h4.z * w2.y;
                    acc[3][0] += h4.w * w2.x; acc[3][1] += h4.w * w2.y;
                }
            }
        }
        {
            const float4 p0 = {acc[0][0], acc[0][1], acc[1][0], acc[1][1]};
            const float4 p1 = {acc[2][0], acc[2][1], acc[3][0], acc[3][1]};
            *(float4*)&part[w * 512 + lane * 8]     = p0;
            *(float4*)&part[w * 512 + lane * 8 + 4] = p1;
        }
        __syncthreads();
        {
            const int o = tid, l = o >> 3, e = o & 7;
            const int b = 4 * (l >> 2) + (e >> 1);
            const int c = 2 * (l & 3) + (e & 1);
            float sum = 0.f;
            #pragma unroll
            for (int ww = 0; ww < 8; ++ww) sum += part[ww * 512 + o];
            const int gcol = (c < 4) ? (wg * 4 + c) : (1024 + wg * 4 + (c - 4));
            const float pre = sum + bhzr[gcol]
                            + sc1Ld(&gx[(size_t)t * GXT + (size_t)b * N3 + gcol]);
            const float sig = 1.f / (1.f + expf(-pre));
            if (c < 4) {
                zl[b * 4 + c] = sig;
            } else {
                const int j = wg * 4 + (c - 4);
                const float rh = sig * hold[b * 4 + (c - 4)];
                sc1St(&gx[(size_t)t * GXT + (size_t)(j >> 4) * 3072
                          + 1024 + (j & 15) * 64 + b], rh);
            }
        }
        grid_bar(&bar[2 * s]);

        // ================= phase B: candidate + h update =================
        float acc2[4][4] = {};
        const int s32 = w * 4 + (lane & 3);   // 32 K-slices of 32
        if (s > 0) {
            const float* rb_ = gx + (size_t)t * GXT + 1024;
            #pragma unroll
            for (int kb2 = 0; kb2 < 2; ++kb2) {
                const float* rowb = rb_ + (size_t)(s32 * 2 + kb2) * 3072;
                const float* wrow = &Whh_l[(s32 * 32 + kb2 * 16) * 4];
                #pragma unroll
                for (int kk = 0; kk < 16; ++kk) {
                    const float4 r4 = *(const float4*)(rowb + kk * 64 + 4 * b4);
                    const float4 w4 = *(const float4*)(wrow + kk * 4);
                    acc2[0][0] += r4.x * w4.x; acc2[0][1] += r4.x * w4.y;
                    acc2[0][2] += r4.x * w4.z; acc2[0][3] += r4.x * w4.w;
                    acc2[1][0] += r4.y * w4.x; acc2[1][1] += r4.y * w4.y;
                    acc2[1][2] += r4.y * w4.z; acc2[1][3] += r4.y * w4.w;
                    acc2[2][0] += r4.z * w4.x; acc2[2][1] += r4.z * w4.y;
                    acc2[2][2] += r4.z * w4.z; acc2[2][3] += r4.z * w4.w;
                    acc2[3][0] += r4.w * w4.x; acc2[3][1] += r4.w * w4.y;
                    acc2[3][2] += r4.w * w4.z; acc2[3][3] += r4.w * w4.w;
                }
            }
        }
        #pragma unroll
        for (int i = 0; i < 4; ++i) {
            const float4 pv = {acc2[i][0], acc2[i][1], acc2[i][2], acc2[i][3]};
            *(float4*)&part[s32 * 260 + b4 * 16 + i * 4] = pv;
        }
        __syncthreads();
        if (tid < 256) {
            const int o = tid;
            const int bb4 = o >> 4, i = (o >> 2) & 3, jc = o & 3;
            const int b = 4 * bb4 + i;
            const int col = wg * 4 + jc;
            float sum = 0.f;
            #pragma unroll
            for (int ss = 0; ss < 32; ++ss) sum += part[ss * 260 + o];
            const float pre = sum + bhh[col]
                            + gx[(size_t)t * GXT + (size_t)b * N3 + 2048 + col];
            const float hc = tanhf(pre);
            const float z = zl[b * 4 + jc];
            const float ho = hold[b * 4 + jc];
            float hn = ho + z * (hc - ho);
            const float mk = mask[t * BATCH + b];
            hn = ho + mk * (hn - ho);
            sc1St(&out[((size_t)t * BATCH + b) * HDIM + col], hn);
            sc1St(&gx[(size_t)t * GXT + (size_t)(col >> 4) * 3072
                      + (col & 15) * 64 + b], hn);
        }
        grid_bar(&bar[2 * s + 1]);
    }
}

// ---------------------------------------------------------------------------
extern "C" void kernel_launch(void* const* d_in, const int* in_sizes, int n_in,
                              void* d_out, int out_size, void* d_ws, size_t ws_size,
                              hipStream_t stream) {
    const int*   xs      = (const int*)  d_in[0];
    const float* xs_mask = (const float*)d_in[1];
    const float* emb     = (const float*)d_in[2];
    const float* fw_Wx   = (const float*)d_in[3];
    const float* fw_bx   = (const float*)d_in[4];
    const float* fw_Whzr = (const float*)d_in[5];
    const float* fw_bhzr = (const float*)d_in[6];
    const float* fw_Whh  = (const float*)d_in[7];
    const float* fw_bhh  = (const float*)d_in[8];
    const float* bw_Wx   = (const float*)d_in[9];
    const float* bw_bx   = (const float*)d_in[10];
    const float* bw_Whzr = (const float*)d_in[11];
    const float* bw_bhzr = (const float*)d_in[12];
    const float* bw_Whh  = (const float*)d_in[13];
    const float* bw_bhh  = (const float*)d_in[14];
    float* outp = (float*)d_out;

    float* gxbuf = (float*)d_ws;
    int*   bar   = (int*)((char*)d_ws + (size_t)LSEQ * GXT * sizeof(float));
    int*   barF  = bar;
    int*   barB  = bar + 2 * LSEQ;

    hipMemsetAsync(bar, 0, 4 * LSEQ * sizeof(int), stream);

    const dim3 gemm_grid(N3 / 64, (LSEQ * BATCH) / 64);
    const dim3 gemm_blk(256);

    // ---- forward: gx = emb[xs] @ fw_Wx + fw_bx ; scan ----
    hipLaunchKernelGGL(gemm_bias, gemm_grid, gemm_blk, 0, stream,
                       emb, xs, EDIM, fw_Wx, fw_bx, gxbuf, N3);
    {
        int rev = 0;
        void* args[] = {(void*)&gxbuf, (void*)&fw_Whzr, (void*)&fw_bhzr,
                        (void*)&fw_Whh, (void*)&fw_bhh, (void*)&xs_mask,
                        (void*)&outp, (void*)&barF, (void*)&rev};
        hipLaunchCooperativeKernel((const void*)gru_scan2, dim3(NWG), dim3(NTH),
                                   args, 0, stream);
    }

    // ---- backward: gx = right(@d_out) @ bw_Wx + bw_bx ; scan ----
    {
        const float* rightp = (const float*)d_out;
        const int* noidx = nullptr;
        hipLaunchKernelGGL(gemm_bias, gemm_grid, gemm_blk, 0, stream,
                           rightp, noidx, HDIM, bw_Wx, bw_bx, gxbuf, N3);
    }
    {
        int rev = 1;
        void* args[] = {(void*)&gxbuf, (void*)&bw_Whzr, (void*)&bw_bhzr,
                        (void*)&bw_Whh, (void*)&bw_bhh, (void*)&xs_mask,
                        (void*)&outp, (void*)&barB, (void*)&rev};
        hipLaunchCooperativeKernel((const void*)gru_scan2, dim3(NWG), dim3(NTH),
                                   args, 0, stream);
    }
}

// Round 3
// 7497.427 us; speedup vs baseline: 9.9574x; 1.0815x over previous
//
#include <hip/hip_runtime.h>
#include <math.h>

#define LSEQ 128
#define BATCH 64
#define EDIM 512
#define HDIM 1024
#define N3 3072
#define NWG 256
#define NTH 512
#define GXT ((size_t)(BATCH * N3))   // floats per time step in gx

// ---------------------------------------------------------------------------
// agent-scope (cross-XCD coherent) scalar load/store
// ---------------------------------------------------------------------------
__device__ __forceinline__ float sc1Ld(const float* p) {
    return __hip_atomic_load(p, __ATOMIC_RELAXED, __HIP_MEMORY_SCOPE_AGENT);
}
__device__ __forceinline__ void sc1St(float* p, float v) {
    __hip_atomic_store(p, v, __ATOMIC_RELAXED, __HIP_MEMORY_SCOPE_AGENT);
}

// Flag-array grid barrier: WG i raises flags[i]=seq (after __syncthreads has
// drained every wave's stores); 256 threads poll all 256 flags in parallel.
// seq is monotone per step -> no re-zeroing, no stale-flag hazard.
__device__ __forceinline__ void flag_bar(int* flags, int seq) {
    __syncthreads();
    if (threadIdx.x == 0)
        __hip_atomic_store(&flags[blockIdx.x], seq,
                           __ATOMIC_RELAXED, __HIP_MEMORY_SCOPE_AGENT);
    if (threadIdx.x < NWG) {
        while (__hip_atomic_load(&flags[threadIdx.x],
                                 __ATOMIC_RELAXED, __HIP_MEMORY_SCOPE_AGENT) < seq)
            __builtin_amdgcn_s_sleep(2);
    }
    __syncthreads();
}

// ---------------------------------------------------------------------------
// f32 tiled GEMM with optional row-gather on A (unchanged).
// ---------------------------------------------------------------------------
__global__ __launch_bounds__(256) void gemm_bias(
    const float* __restrict__ A, const int* __restrict__ idx, int K,
    const float* __restrict__ Bm, const float* __restrict__ bias,
    float* __restrict__ C, int N)
{
    __shared__ float As[32][68];
    __shared__ float Bs[32][68];
    const int tid = threadIdx.x;
    const int m0 = blockIdx.y * 64, n0 = blockIdx.x * 64;
    const int ty = tid >> 4, tx = tid & 15;

    float acc[4][4] = {};

    const int ra = tid >> 3;
    const int kq = (tid & 7) << 2;
    const int kb = tid >> 4;
    const int nq = (tid & 15) << 2;

    for (int k0 = 0; k0 < K; k0 += 32) {
        #pragma unroll
        for (int h2 = 0; h2 < 2; ++h2) {
            const int row = ra + h2 * 32;
            const int grow = idx ? idx[m0 + row] : (m0 + row);
            const float4 v = *reinterpret_cast<const float4*>(&A[(size_t)grow * K + k0 + kq]);
            As[kq + 0][row] = v.x; As[kq + 1][row] = v.y;
            As[kq + 2][row] = v.z; As[kq + 3][row] = v.w;
        }
        #pragma unroll
        for (int h2 = 0; h2 < 2; ++h2) {
            const int kk = kb + h2 * 16;
            *reinterpret_cast<float4*>(&Bs[kk][nq]) =
                *reinterpret_cast<const float4*>(&Bm[(size_t)(k0 + kk) * N + n0 + nq]);
        }
        __syncthreads();
        #pragma unroll
        for (int k = 0; k < 32; ++k) {
            const float4 a4 = *reinterpret_cast<const float4*>(&As[k][ty * 4]);
            const float4 b4 = *reinterpret_cast<const float4*>(&Bs[k][tx * 4]);
            const float av[4] = {a4.x, a4.y, a4.z, a4.w};
            const float bv[4] = {b4.x, b4.y, b4.z, b4.w};
            #pragma unroll
            for (int i = 0; i < 4; ++i)
                #pragma unroll
                for (int j = 0; j < 4; ++j)
                    acc[i][j] += av[i] * bv[j];
        }
        __syncthreads();
    }
    #pragma unroll
    for (int i = 0; i < 4; ++i) {
        const int m = m0 + ty * 4 + i;
        #pragma unroll
        for (int j = 0; j < 4; ++j) {
            const int n = n0 + tx * 4 + j;
            C[(size_t)m * N + n] = acc[i][j] + bias[n];
        }
    }
}

// ---------------------------------------------------------------------------
// GRU scan v3.
// h(t)/rh(t) live TRANSPOSED [j-chunk][(j&15)*64+b] in the z-/r-regions of the
// PREVIOUS step's gx block (consumed 2 barriers earlier -> race-free), with a
// dedicated scratch block (scr) for the s=0 boundary:
//   zone(u) = (0<=u<L) ? gx + u*GXT : scr ;  u = t-1 (fwd) / t+1 (bwd)
//   h(t)  at zone(u) + (j>>4)*3072 +        (j&15)*64 + b   (sc1-written)
//   rh(t) at zone(u) + (j>>4)*3072 + 1024 + (j&15)*64 + b   (sc1-written)
// Gate gx values are consumed ONLY via sc1 loads (never cached), so the
// later overlay writes can't be shadowed by stale L2 lines; overlay data is
// plain-read only at fresh (never-cached) addresses after a barrier.
// ---------------------------------------------------------------------------
__global__ __launch_bounds__(NTH) void gru_scan3(
    float* __restrict__ gx,           // [L][B][3072]
    float* __restrict__ scr,          // [B][3072] boundary zone
    const float* __restrict__ Whzr,   // [1024][2048]
    const float* __restrict__ bhzr,   // [2048]
    const float* __restrict__ Whh,    // [1024][1024]
    const float* __restrict__ bhh,    // [1024]
    const float* __restrict__ mask,   // [L][B]
    float* __restrict__ out,          // [L][B][1024]
    int* __restrict__ flags,          // [NWG] pre-zeroed
    int reverse)
{
    __shared__ float Wzr_l[HDIM * 8];         // [k][8 cols]
    __shared__ float Whh_l[HDIM * 4 + 128];   // [k][4] + 4-float pad per 32 k
    __shared__ float part[8704];
    __shared__ float zl[BATCH * 4];
    __shared__ float hold[BATCH * 4];

    const int wg = blockIdx.x, tid = threadIdx.x;
    const int w = tid >> 6, lane = tid & 63;
    const int b4 = lane >> 2, c2 = lane & 3;

    // one-time weight staging (coalesced float4 rows)
    for (int k = tid; k < HDIM; k += NTH) {
        *(float4*)&Wzr_l[k * 8]     = *(const float4*)&Whzr[(size_t)k * 2048 + wg * 4];
        *(float4*)&Wzr_l[k * 8 + 4] = *(const float4*)&Whzr[(size_t)k * 2048 + 1024 + wg * 4];
        *(float4*)&Whh_l[k * 4 + (k >> 5) * 4] =
            *(const float4*)&Whh[(size_t)k * HDIM + wg * 4];
    }

    // fixed per-thread reduce mappings + hoisted biases
    const int bA_ = tid >> 3, cA = tid & 7;                 // phase A out elem
    const int gcolA = (cA < 4) ? (wg * 4 + cA) : (1024 + wg * 4 + (cA - 4));
    const float bzrA = bhzr[gcolA];
    const int lsA  = (bA_ >> 2) * 4 + (cA >> 1);
    const int offA = (((bA_ & 3) >= 2) ? 256 : 0) + lsA * 4 + (bA_ & 1) * 2 + (cA & 1);
    const int bb4 = tid >> 4, iB = (tid >> 2) & 3, jcB = tid & 3;  // phase B
    const int bB = 4 * bb4 + iB;
    const int colB = wg * 4 + jcB;
    const float bhhB = bhh[colB];

    __syncthreads();

    for (int s = 0; s < LSEQ; ++s) {
        const int t  = reverse ? (LSEQ - 1 - s) : s;
        const int u  = reverse ? (t + 1) : (t - 1);   // zone holding h(t), rh(t)
        const int up = reverse ? (t + 2) : (t - 2);   // zone holding h(t_prev)
        float* zoneU = (u >= 0 && u < LSEQ) ? (gx + (size_t)u * GXT) : scr;
        const float* zoneP = (up >= 0 && up < LSEQ) ? (gx + (size_t)up * GXT) : scr;

        // ================= phase A: z, r, r*h =================
        // prefetch this thread's gate value (sc1: no cache allocation)
        const float gateA = sc1Ld(&gx[(size_t)t * GXT + (size_t)bA_ * N3 + gcolA]);

        if (tid < 64) {   // stage h_old at this WG's 4 candidate cols
            const int jj = tid >> 4, bq = tid & 15;
            float4 h4 = make_float4(0.f, 0.f, 0.f, 0.f);
            if (s > 0) {
                const int j = wg * 4 + jj;
                h4 = *(const float4*)&zoneP[(size_t)(j >> 4) * 3072 + (j & 15) * 64 + 4 * bq];
            }
            hold[(4 * bq + 0) * 4 + jj] = h4.x;
            hold[(4 * bq + 1) * 4 + jj] = h4.y;
            hold[(4 * bq + 2) * 4 + jj] = h4.z;
            hold[(4 * bq + 3) * 4 + jj] = h4.w;
        }

        float acc[4][2] = {{0.f,0.f},{0.f,0.f},{0.f,0.f},{0.f,0.f}};
        if (s > 0) {
            for (int kb = 0; kb < 8; ++kb) {
                const float* rowb = zoneP + (size_t)(w * 8 + kb) * 3072;
                const float* wrow = &Wzr_l[(w * 128 + kb * 16) * 8 + 2 * c2];
                #pragma unroll
                for (int kk = 0; kk < 16; ++kk) {
                    const float4 h4 = *(const float4*)(rowb + kk * 64 + 4 * b4);
                    const float2 w2 = *(const float2*)(wrow + kk * 8);
                    acc[0][0] += h4.x * w2.x; acc[0][1] += h4.x * w2.y;
                    acc[1][0] += h4.y * w2.x; acc[1][1] += h4.y * w2.y;
                    acc[2][0] += h4.z * w2.x; acc[2][1] += h4.z * w2.y;
                    acc[3][0] += h4.w * w2.x; acc[3][1] += h4.w * w2.y;
                }
            }
        }
        {   // conflict-free partial store: consecutive 16B per lane
            const float4 p0 = {acc[0][0], acc[0][1], acc[1][0], acc[1][1]};
            const float4 p1 = {acc[2][0], acc[2][1], acc[3][0], acc[3][1]};
            *(float4*)&part[w * 512 + lane * 4]       = p0;
            *(float4*)&part[w * 512 + 256 + lane * 4] = p1;
        }
        __syncthreads();
        {
            float sum = 0.f;
            #pragma unroll
            for (int ww = 0; ww < 8; ++ww) sum += part[ww * 512 + offA];
            const float pre = sum + bzrA + gateA;
            const float sig = 1.f / (1.f + expf(-pre));
            if (cA < 4) {
                zl[bA_ * 4 + cA] = sig;
            } else {
                const int j = wg * 4 + (cA - 4);
                const float rh = sig * hold[bA_ * 4 + (cA - 4)];
                sc1St(&zoneU[(size_t)(j >> 4) * 3072 + 1024 + (j & 15) * 64 + bA_], rh);
            }
        }
        flag_bar(flags, 2 * s + 1);

        // ================= phase B: candidate + h update =================
        const float gxc = gx[(size_t)t * GXT + (size_t)bB * N3 + 2048 + colB];
        const float mk  = mask[t * BATCH + bB];

        float acc2[4][4] = {};
        const int s32 = w * 4 + (lane & 3);
        if (s > 0) {
            #pragma unroll
            for (int kb2 = 0; kb2 < 2; ++kb2) {
                const float* rowb = zoneU + 1024 + (size_t)(s32 * 2 + kb2) * 3072;
                const float* wrow = &Whh_l[(s32 * 32 + kb2 * 16) * 4 + s32 * 4];
                #pragma unroll
                for (int kk = 0; kk < 16; ++kk) {
                    const float4 r4 = *(const float4*)(rowb + kk * 64 + 4 * b4);
                    const float4 w4 = *(const float4*)(wrow + kk * 4);
                    acc2[0][0] += r4.x * w4.x; acc2[0][1] += r4.x * w4.y;
                    acc2[0][2] += r4.x * w4.z; acc2[0][3] += r4.x * w4.w;
                    acc2[1][0] += r4.y * w4.x; acc2[1][1] += r4.y * w4.y;
                    acc2[1][2] += r4.y * w4.z; acc2[1][3] += r4.y * w4.w;
                    acc2[2][0] += r4.z * w4.x; acc2[2][1] += r4.z * w4.y;
                    acc2[2][2] += r4.z * w4.z; acc2[2][3] += r4.z * w4.w;
                    acc2[3][0] += r4.w * w4.x; acc2[3][1] += r4.w * w4.y;
                    acc2[3][2] += r4.w * w4.z; acc2[3][3] += r4.w * w4.w;
                }
            }
        }
        #pragma unroll
        for (int i = 0; i < 4; ++i) {
            const float4 pv = {acc2[i][0], acc2[i][1], acc2[i][2], acc2[i][3]};
            *(float4*)&part[s32 * 260 + b4 * 16 + i * 4] = pv;
        }
        __syncthreads();
        if (tid < 256) {
            float sum = 0.f;
            #pragma unroll
            for (int ss = 0; ss < 32; ++ss) sum += part[ss * 260 + tid];
            const float pre = sum + bhhB + gxc;
            const float hc = tanhf(pre);
            const float z  = zl[bB * 4 + jcB];
            const float ho = hold[bB * 4 + jcB];
            float hn = ho + z * (hc - ho);
            hn = ho + mk * (hn - ho);
            out[((size_t)t * BATCH + bB) * HDIM + colB] = hn;   // plain (kernel-end flush)
            sc1St(&zoneU[(size_t)(colB >> 4) * 3072 + (colB & 15) * 64 + bB], hn);
        }
        flag_bar(flags, 2 * s + 2);
    }
}

// ---------------------------------------------------------------------------
extern "C" void kernel_launch(void* const* d_in, const int* in_sizes, int n_in,
                              void* d_out, int out_size, void* d_ws, size_t ws_size,
                              hipStream_t stream) {
    const int*   xs      = (const int*)  d_in[0];
    const float* xs_mask = (const float*)d_in[1];
    const float* emb     = (const float*)d_in[2];
    const float* fw_Wx   = (const float*)d_in[3];
    const float* fw_bx   = (const float*)d_in[4];
    const float* fw_Whzr = (const float*)d_in[5];
    const float* fw_bhzr = (const float*)d_in[6];
    const float* fw_Whh  = (const float*)d_in[7];
    const float* fw_bhh  = (const float*)d_in[8];
    const float* bw_Wx   = (const float*)d_in[9];
    const float* bw_bx   = (const float*)d_in[10];
    const float* bw_Whzr = (const float*)d_in[11];
    const float* bw_bhzr = (const float*)d_in[12];
    const float* bw_Whh  = (const float*)d_in[13];
    const float* bw_bhh  = (const float*)d_in[14];
    float* outp = (float*)d_out;

    char* wp = (char*)d_ws;
    float* gxbuf = (float*)wp; wp += (size_t)LSEQ * GXT * sizeof(float);   // 100.7 MB
    float* scr   = (float*)wp; wp += GXT * sizeof(float);                  // 768 KB
    int* flagsF  = (int*)wp;   wp += NWG * sizeof(int);
    int* flagsB  = (int*)wp;   wp += NWG * sizeof(int);

    hipMemsetAsync(flagsF, 0, 2 * NWG * sizeof(int), stream);

    const dim3 gemm_grid(N3 / 64, (LSEQ * BATCH) / 64);
    const dim3 gemm_blk(256);

    // ---- forward: gx = emb[xs] @ fw_Wx + fw_bx ; scan ----
    hipLaunchKernelGGL(gemm_bias, gemm_grid, gemm_blk, 0, stream,
                       emb, xs, EDIM, fw_Wx, fw_bx, gxbuf, N3);
    {
        int rev = 0;
        void* args[] = {(void*)&gxbuf, (void*)&scr, (void*)&fw_Whzr, (void*)&fw_bhzr,
                        (void*)&fw_Whh, (void*)&fw_bhh, (void*)&xs_mask,
                        (void*)&outp, (void*)&flagsF, (void*)&rev};
        hipLaunchCooperativeKernel((const void*)gru_scan3, dim3(NWG), dim3(NTH),
                                   args, 0, stream);
    }

    // ---- backward: gx = right(@d_out) @ bw_Wx + bw_bx ; scan ----
    {
        const float* rightp = (const float*)d_out;
        const int* noidx = nullptr;
        hipLaunchKernelGGL(gemm_bias, gemm_grid, gemm_blk, 0, stream,
                           rightp, noidx, HDIM, bw_Wx, bw_bx, gxbuf, N3);
    }
    {
        int rev = 1;
        void* args[] = {(void*)&gxbuf, (void*)&scr, (void*)&bw_Whzr, (void*)&bw_bhzr,
                        (void*)&bw_Whh, (void*)&bw_bhh, (void*)&xs_mask,
                        (void*)&outp, (void*)&flagsB, (void*)&rev};
        hipLaunchCooperativeKernel((const void*)gru_scan3, dim3(NWG), dim3(NTH),
                                   args, 0, stream);
    }
}

// Round 4
// 7463.679 us; speedup vs baseline: 10.0024x; 1.0045x over previous
//
#include <hip/hip_runtime.h>
#include <math.h>

#define LSEQ 128
#define BATCH 64
#define EDIM 512
#define HDIM 1024
#define N3 3072
#define NWG 256
#define NTH 512
#define GXT ((size_t)(N3 * BATCH))   // floats per time step in gxT ([3072][64])

// ---------------------------------------------------------------------------
// agent-scope (cross-XCD coherent) scalar load/store
// ---------------------------------------------------------------------------
__device__ __forceinline__ float sc1Ld(const float* p) {
    return __hip_atomic_load(p, __ATOMIC_RELAXED, __HIP_MEMORY_SCOPE_AGENT);
}
__device__ __forceinline__ void sc1St(float* p, float v) {
    __hip_atomic_store(p, v, __ATOMIC_RELAXED, __HIP_MEMORY_SCOPE_AGENT);
}

// Counter barrier: one fresh counter per barrier instance (pre-zeroed, monotone
// use), ONE arriving atomicAdd and ONE poller per WG. __syncthreads drains all
// waves' sc1 stores to the coherent point before thread 0 arrives.
__device__ __forceinline__ void cnt_bar(int* cnt) {
    __syncthreads();
    if (threadIdx.x == 0) {
        asm volatile("s_waitcnt vmcnt(0)" ::: "memory");
        __hip_atomic_fetch_add(cnt, 1, __ATOMIC_RELAXED, __HIP_MEMORY_SCOPE_AGENT);
        while (__hip_atomic_load(cnt, __ATOMIC_RELAXED, __HIP_MEMORY_SCOPE_AGENT) < NWG)
            __builtin_amdgcn_s_sleep(2);
    }
    __syncthreads();
}

// ---------------------------------------------------------------------------
// f32 tiled GEMM, optional row-gather on A. Output written BLOCK-TRANSPOSED:
//   C[(m>>6)][n][m&63]  (i.e. gxT layout [t][3072][64]); tile is staged
//   through LDS so global stores are coalesced along m.
// ---------------------------------------------------------------------------
__global__ __launch_bounds__(256) void gemm_biasT(
    const float* __restrict__ A, const int* __restrict__ idx, int K,
    const float* __restrict__ Bm, const float* __restrict__ bias,
    float* __restrict__ C, int N)
{
    __shared__ float Sm[4352];          // As[32][68] @0, Bs[32][68] @2176
    float* As = Sm;
    float* Bs = Sm + 2176;
    const int tid = threadIdx.x;
    const int m0 = blockIdx.y * 64, n0 = blockIdx.x * 64;
    const int ty = tid >> 4, tx = tid & 15;

    float acc[4][4] = {};

    const int ra = tid >> 3;
    const int kq = (tid & 7) << 2;
    const int kb = tid >> 4;
    const int nq = (tid & 15) << 2;

    for (int k0 = 0; k0 < K; k0 += 32) {
        #pragma unroll
        for (int h2 = 0; h2 < 2; ++h2) {
            const int row = ra + h2 * 32;
            const int grow = idx ? idx[m0 + row] : (m0 + row);
            const float4 v = *reinterpret_cast<const float4*>(&A[(size_t)grow * K + k0 + kq]);
            As[(kq + 0) * 68 + row] = v.x; As[(kq + 1) * 68 + row] = v.y;
            As[(kq + 2) * 68 + row] = v.z; As[(kq + 3) * 68 + row] = v.w;
        }
        #pragma unroll
        for (int h2 = 0; h2 < 2; ++h2) {
            const int kk = kb + h2 * 16;
            *reinterpret_cast<float4*>(&Bs[kk * 68 + nq]) =
                *reinterpret_cast<const float4*>(&Bm[(size_t)(k0 + kk) * N + n0 + nq]);
        }
        __syncthreads();
        #pragma unroll
        for (int k = 0; k < 32; ++k) {
            const float4 a4 = *reinterpret_cast<const float4*>(&As[k * 68 + ty * 4]);
            const float4 b4 = *reinterpret_cast<const float4*>(&Bs[k * 68 + tx * 4]);
            const float av[4] = {a4.x, a4.y, a4.z, a4.w};
            const float bv[4] = {b4.x, b4.y, b4.z, b4.w};
            #pragma unroll
            for (int i = 0; i < 4; ++i)
                #pragma unroll
                for (int j = 0; j < 4; ++j)
                    acc[i][j] += av[i] * bv[j];
        }
        __syncthreads();
    }

    // epilogue: stage [m][n] (stride 65), then coalesced-along-m global stores
    #pragma unroll
    for (int i = 0; i < 4; ++i) {
        float4 v = {acc[i][0] + bias[n0 + tx * 4 + 0],
                    acc[i][1] + bias[n0 + tx * 4 + 1],
                    acc[i][2] + bias[n0 + tx * 4 + 2],
                    acc[i][3] + bias[n0 + tx * 4 + 3]};
        *reinterpret_cast<float4*>(&Sm[(ty * 4 + i) * 65 + tx * 4]) = v;
    }
    __syncthreads();
    const int mloc = tid & 63, nq2 = tid >> 6;    // nq2: 0..3
    const size_t base = (size_t)blockIdx.y * ((size_t)N * 64) + (size_t)n0 * 64;
    #pragma unroll
    for (int q = 0; q < 16; ++q) {
        const int nl = nq2 * 16 + q;
        C[base + (size_t)nl * 64 + mloc] = Sm[mloc * 65 + nl];
    }
}

// ---------------------------------------------------------------------------
// GRU scan v4 — transposed gx layout [t][3072][64].
//   z gates:    gxT[t][c][b],        c in [0,1024)   (sc1-read at A(t))
//   r gates:    gxT[t][1024+c][b]                    (sc1-read at A(t))
//   cand gates: gxT[t][2048+c][b]                    (plain-read at B(t), never overlaid)
// Overlays (into PREVIOUS step's consumed zone u = t-1 fwd / t+1 bwd; scr at boundary):
//   h(t)  -> zone(u)[c][b]        (sc1-written at B(t))
//   rh(t) -> zone(u)[1024+c][b]   (sc1-written at A(t))
// All gate regions are consumed only via sc1 (no cache allocation), so later
// overlay writes cannot be shadowed; overlay data is plain-read only at fresh
// addresses after a barrier. Boundary zone scr is written before any read.
// ---------------------------------------------------------------------------
__global__ __launch_bounds__(NTH) void gru_scan4(
    float* __restrict__ gxT,
    float* __restrict__ scr,
    const float* __restrict__ Whzr,   // [1024][2048]
    const float* __restrict__ bhzr,
    const float* __restrict__ Whh,    // [1024][1024]
    const float* __restrict__ bhh,
    const float* __restrict__ mask,   // [L][B]
    float* __restrict__ out,          // [L][B][1024]
    int* __restrict__ bar,            // [2*LSEQ] pre-zeroed
    int reverse)
{
    __shared__ float Wzr_l[HDIM * 8];         // [k][8 cols]
    __shared__ float Whh_l[HDIM * 4 + 128];   // [k][4] + pad per 32 k
    __shared__ float part[8320];
    __shared__ float zl[256];                 // [b][4]
    __shared__ float hold[256];               // [b][4]

    const int wg = blockIdx.x, tid = threadIdx.x;
    const int w = tid >> 6, lane = tid & 63;
    const int b4 = lane >> 2, c2 = lane & 3;

    // one-time weight staging
    for (int k = tid; k < HDIM; k += NTH) {
        *(float4*)&Wzr_l[k * 8]     = *(const float4*)&Whzr[(size_t)k * 2048 + wg * 4];
        *(float4*)&Wzr_l[k * 8 + 4] = *(const float4*)&Whzr[(size_t)k * 2048 + 1024 + wg * 4];
        *(float4*)&Whh_l[k * 4 + (k >> 5) * 4] =
            *(const float4*)&Whh[(size_t)k * HDIM + wg * 4];
    }

    // phase-A per-thread constants: output (bA, cA), cA in 0..7
    const int cA = tid >> 6, bA = tid & 63;
    const int gcA = (cA < 4) ? (wg * 4 + cA) : (1024 + wg * 4 + (cA - 4));
    const float bzrA = bhzr[gcA];
    const int iA = bA & 3;
    const int offA = ((iA >= 2) ? 256 : 0) + ((bA >> 2) * 4 + (cA >> 1)) * 4
                   + (iA & 1) * 2 + (cA & 1);
    // phase-B per-thread constants (tid<256 active): output (bB, colB)
    const int colB = (tid >> 6) & 3, bB = tid & 63;
    const float bhhB = bhh[wg * 4 + colB];
    const int offB = (bB >> 2) * 16 + (bB & 3) * 4 + colB;
    const int s32 = w * 4 + c2;

    __syncthreads();

    // prefetch step-0 gate (pure input; coalesced sc1)
    float gateA = sc1Ld(&gxT[(size_t)(reverse ? LSEQ - 1 : 0) * GXT + (size_t)gcA * 64 + bA]);

    for (int s = 0; s < LSEQ; ++s) {
        const int t  = reverse ? (LSEQ - 1 - s) : s;
        const int u  = reverse ? (t + 1) : (t - 1);
        const int up = reverse ? (t + 2) : (t - 2);
        float* zoneU = (u >= 0 && u < LSEQ) ? (gxT + (size_t)u * GXT) : scr;
        const float* zoneP = (up >= 0 && up < LSEQ) ? (gxT + (size_t)up * GXT) : scr;

        // prefetch phase-B inputs (pure inputs: cand region never overlaid)
        float gxcB = 0.f, mkB = 0.f;
        if (tid < 256) {
            gxcB = gxT[(size_t)t * GXT + (size_t)(2048 + wg * 4 + colB) * 64 + bB];
            mkB  = mask[t * BATCH + bB];
            float hv = 0.f;
            if (s > 0) hv = zoneP[(size_t)(wg * 4 + colB) * 64 + bB];
            hold[bB * 4 + colB] = hv;
        }

        // ---------- phase A GEMM: gh_zr, wave w owns K-slice [128w,128w+128) ----------
        float acc[4][2] = {{0.f,0.f},{0.f,0.f},{0.f,0.f},{0.f,0.f}};
        if (s > 0) {
            const float* hbase = zoneP + (size_t)(w * 128) * 64;
            for (int kb = 0; kb < 8; ++kb) {
                const float* rowb = hbase + kb * 16 * 64;
                const float* wrow = &Wzr_l[(w * 128 + kb * 16) * 8 + 2 * c2];
                #pragma unroll
                for (int kk = 0; kk < 16; ++kk) {
                    const float4 h4 = *(const float4*)(rowb + kk * 64 + 4 * b4);
                    const float2 w2 = *(const float2*)(wrow + kk * 8);
                    acc[0][0] += h4.x * w2.x; acc[0][1] += h4.x * w2.y;
                    acc[1][0] += h4.y * w2.x; acc[1][1] += h4.y * w2.y;
                    acc[2][0] += h4.z * w2.x; acc[2][1] += h4.z * w2.y;
                    acc[3][0] += h4.w * w2.x; acc[3][1] += h4.w * w2.y;
                }
            }
        }
        {
            const float4 p0 = {acc[0][0], acc[0][1], acc[1][0], acc[1][1]};
            const float4 p1 = {acc[2][0], acc[2][1], acc[3][0], acc[3][1]};
            *(float4*)&part[w * 512 + lane * 4]       = p0;
            *(float4*)&part[w * 512 + 256 + lane * 4] = p1;
        }
        __syncthreads();
        {
            float sum = 0.f;
            #pragma unroll
            for (int ww = 0; ww < 8; ++ww) sum += part[ww * 512 + offA];
            const float pre = sum + bzrA + gateA;
            const float sig = 1.f / (1.f + expf(-pre));
            if (cA < 4) {
                zl[bA * 4 + cA] = sig;
            } else {
                const float rh = sig * hold[bA * 4 + (cA - 4)];
                sc1St(&zoneU[(size_t)(1024 + wg * 4 + (cA - 4)) * 64 + bA], rh);
            }
        }
        cnt_bar(&bar[2 * s]);

        // prefetch next step's gate (pure input region at t_next; safe anytime)
        if (s + 1 < LSEQ) {
            const int tn = reverse ? (t - 1) : (t + 1);
            gateA = sc1Ld(&gxT[(size_t)tn * GXT + (size_t)gcA * 64 + bA]);
        }

        // ---------- phase B GEMM: candidate, 32 K-slices of 32 ----------
        float acc2[4][4] = {};
        if (s > 0) {
            const float* rbase = zoneU + (size_t)(1024 + s32 * 32) * 64;
            #pragma unroll
            for (int kb2 = 0; kb2 < 2; ++kb2) {
                const float* rowb = rbase + kb2 * 16 * 64;
                const float* wrow = &Whh_l[(s32 * 32 + kb2 * 16) * 4 + s32 * 4];
                #pragma unroll
                for (int kk = 0; kk < 16; ++kk) {
                    const float4 r4 = *(const float4*)(rowb + kk * 64 + 4 * b4);
                    const float4 w4 = *(const float4*)(wrow + kk * 4);
                    acc2[0][0] += r4.x * w4.x; acc2[0][1] += r4.x * w4.y;
                    acc2[0][2] += r4.x * w4.z; acc2[0][3] += r4.x * w4.w;
                    acc2[1][0] += r4.y * w4.x; acc2[1][1] += r4.y * w4.y;
                    acc2[1][2] += r4.y * w4.z; acc2[1][3] += r4.y * w4.w;
                    acc2[2][0] += r4.z * w4.x; acc2[2][1] += r4.z * w4.y;
                    acc2[2][2] += r4.z * w4.z; acc2[2][3] += r4.z * w4.w;
                    acc2[3][0] += r4.w * w4.x; acc2[3][1] += r4.w * w4.y;
                    acc2[3][2] += r4.w * w4.z; acc2[3][3] += r4.w * w4.w;
                }
            }
        }
        #pragma unroll
        for (int i = 0; i < 4; ++i) {
            const float4 pv = {acc2[i][0], acc2[i][1], acc2[i][2], acc2[i][3]};
            *(float4*)&part[s32 * 260 + b4 * 16 + i * 4] = pv;
        }
        __syncthreads();
        if (tid < 256) {
            float sum = 0.f;
            #pragma unroll
            for (int ss = 0; ss < 32; ++ss) sum += part[ss * 260 + offB];
            const float pre = sum + bhhB + gxcB;
            const float hc = tanhf(pre);
            const float z  = zl[bB * 4 + colB];
            const float ho = hold[bB * 4 + colB];
            float hn = ho + z * (hc - ho);
            hn = ho + mkB * (hn - ho);
            out[((size_t)t * BATCH + bB) * HDIM + wg * 4 + colB] = hn;
            sc1St(&zoneU[(size_t)(wg * 4 + colB) * 64 + bB], hn);
        }
        cnt_bar(&bar[2 * s + 1]);
    }
}

// ---------------------------------------------------------------------------
extern "C" void kernel_launch(void* const* d_in, const int* in_sizes, int n_in,
                              void* d_out, int out_size, void* d_ws, size_t ws_size,
                              hipStream_t stream) {
    const int*   xs      = (const int*)  d_in[0];
    const float* xs_mask = (const float*)d_in[1];
    const float* emb     = (const float*)d_in[2];
    const float* fw_Wx   = (const float*)d_in[3];
    const float* fw_bx   = (const float*)d_in[4];
    const float* fw_Whzr = (const float*)d_in[5];
    const float* fw_bhzr = (const float*)d_in[6];
    const float* fw_Whh  = (const float*)d_in[7];
    const float* fw_bhh  = (const float*)d_in[8];
    const float* bw_Wx   = (const float*)d_in[9];
    const float* bw_bx   = (const float*)d_in[10];
    const float* bw_Whzr = (const float*)d_in[11];
    const float* bw_bhzr = (const float*)d_in[12];
    const float* bw_Whh  = (const float*)d_in[13];
    const float* bw_bhh  = (const float*)d_in[14];
    float* outp = (float*)d_out;

    char* wp = (char*)d_ws;
    float* gxbuf = (float*)wp; wp += (size_t)LSEQ * GXT * sizeof(float);   // 100.7 MB
    float* scr   = (float*)wp; wp += GXT * sizeof(float);                  // 768 KB
    int* barF    = (int*)wp;   wp += 2 * LSEQ * sizeof(int);
    int* barB    = (int*)wp;   wp += 2 * LSEQ * sizeof(int);

    hipMemsetAsync(barF, 0, 4 * LSEQ * sizeof(int), stream);

    const dim3 gemm_grid(N3 / 64, (LSEQ * BATCH) / 64);
    const dim3 gemm_blk(256);

    // ---- forward: gxT = (emb[xs] @ fw_Wx + fw_bx)^T-per-step ; scan ----
    hipLaunchKernelGGL(gemm_biasT, gemm_grid, gemm_blk, 0, stream,
                       emb, xs, EDIM, fw_Wx, fw_bx, gxbuf, N3);
    {
        int rev = 0;
        void* args[] = {(void*)&gxbuf, (void*)&scr, (void*)&fw_Whzr, (void*)&fw_bhzr,
                        (void*)&fw_Whh, (void*)&fw_bhh, (void*)&xs_mask,
                        (void*)&outp, (void*)&barF, (void*)&rev};
        hipLaunchCooperativeKernel((const void*)gru_scan4, dim3(NWG), dim3(NTH),
                                   args, 0, stream);
    }

    // ---- backward: gxT = (right @ bw_Wx + bw_bx)^T-per-step ; scan ----
    {
        const float* rightp = (const float*)d_out;
        const int* noidx = nullptr;
        hipLaunchKernelGGL(gemm_biasT, gemm_grid, gemm_blk, 0, stream,
                           rightp, noidx, HDIM, bw_Wx, bw_bx, gxbuf, N3);
    }
    {
        int rev = 1;
        void* args[] = {(void*)&gxbuf, (void*)&scr, (void*)&bw_Whzr, (void*)&bw_bhzr,
                        (void*)&bw_Whh, (void*)&bw_bhh, (void*)&xs_mask,
                        (void*)&outp, (void*)&barB, (void*)&rev};
        hipLaunchCooperativeKernel((const void*)gru_scan4, dim3(NWG), dim3(NTH),
                                   args, 0, stream);
    }
}